// Round 6
// baseline (729.176 us; speedup 1.0000x reference)
//
#include <hip/hip_runtime.h>
#include <hip/hip_bf16.h>
#include <math.h>

#define B_ 4
#define N_ 4096
#define D_ 768
#define KTOP 8
#define M_ (B_*N_)          // 16384
#define TCAND 12            // bf16 candidates kept per row (margin over KTOP=8)
#define KSPLIT 16           // k-range splits in select kernel (256 k each)
#define QBK 32              // qkv_mfma K-step (32 KB total LDS -> 4-5 blocks/CU)

typedef __attribute__((ext_vector_type(8))) short short8;
typedef __attribute__((ext_vector_type(4))) float f32x4;
typedef _Float16 half_t;
typedef __attribute__((ext_vector_type(8))) _Float16 half8;
typedef __attribute__((ext_vector_type(4))) _Float16 half4;

__device__ __forceinline__ ushort f2bf(float f) {
    unsigned int u = __float_as_uint(f);
    unsigned int r = (u + 0x7FFFu + ((u >> 16) & 1u)) >> 16;
    return (ushort)r;
}

__device__ __forceinline__ void gload16(const void* g, void* l) {
    __builtin_amdgcn_global_load_lds(
        (const __attribute__((address_space(1))) unsigned int*)g,
        (__attribute__((address_space(3))) unsigned int*)l, 16, 0, 0);
}

// ---------------------------------------------------------------------------
// Kernel 1a: split feats into fp16 hi/lo (Dekker 2-way split).
// ---------------------------------------------------------------------------
__global__ __launch_bounds__(256) void split_feats(
    const float* __restrict__ f, half_t* __restrict__ Fh, half_t* __restrict__ Fl)
{
    const int i = (blockIdx.x * 256 + threadIdx.x) * 4;   // exact coverage
    const float4 v = *(const float4*)&f[i];
    float x[4] = {v.x, v.y, v.z, v.w};
    half4 h, l;
#pragma unroll
    for (int c = 0; c < 4; ++c) {
        const half_t hh = (half_t)x[c];
        h[c] = hh;
        l[c] = (half_t)(x[c] - (float)hh);
    }
    *(half4*)&Fh[i] = h;
    *(half4*)&Fl[i] = l;
}

// ---------------------------------------------------------------------------
// Kernel 1b: build W^T fp16 hi/lo splits, scaled by 2^12 (exact).
// ---------------------------------------------------------------------------
__global__ __launch_bounds__(256) void split_w(
    const float* __restrict__ Wq, const float* __restrict__ Wkv,
    half_t* __restrict__ Wth, half_t* __restrict__ Wtl)
{
    __shared__ float T[64][65];
    const int tid = threadIdx.x;
    const int n0 = blockIdx.x * 64;     // dest row block (output col)
    const int k0 = blockIdx.y * 64;     // dest col block (contraction)

    const int nl = tid & 63;
#pragma unroll
    for (int r = 0; r < 16; ++r) {
        const int kl = (tid >> 6) * 16 + r;
        const int n  = n0 + nl;
        const float w = (n < 768)
            ? Wq[(size_t)(k0 + kl) * 768 + n]
            : Wkv[(size_t)(k0 + kl) * 1536 + (n - 768)];
        T[kl][nl] = w;
    }
    __syncthreads();

    const int kl2 = tid & 63;
#pragma unroll
    for (int r = 0; r < 16; ++r) {
        const int nl2 = (tid >> 6) * 16 + r;
        const float ws = T[kl2][nl2] * 4096.0f;
        const half_t h = (half_t)ws;
        const half_t l = (half_t)(ws - (float)h);
        Wth[(size_t)(n0 + nl2) * D_ + k0 + kl2] = h;
        Wtl[(size_t)(n0 + nl2) * D_ + k0 + kl2] = l;
    }
}

// ---------------------------------------------------------------------------
// Kernel 1c: QKV projection via fp16-split MFMA. BK=32 (32 KB LDS total:
// occupancy fix vs round-5's 64 KB / 2 blocks/CU, m132 regression mode).
// QK region: 3 MFMA terms (hh, hl, lh); V region: hh only.
// ---------------------------------------------------------------------------
__global__ __launch_bounds__(256) void qkv_mfma(
    const half_t* __restrict__ Fh, const half_t* __restrict__ Fl,
    const half_t* __restrict__ Wth, const half_t* __restrict__ Wtl,
    const float* __restrict__ bq, const float* __restrict__ bkv,
    float* __restrict__ Q, float* __restrict__ Km, float* __restrict__ Vm)
{
    __shared__ __align__(16) half_t Ah[128 * QBK];   // 8 KB each
    __shared__ __align__(16) half_t Al[128 * QBK];
    __shared__ __align__(16) half_t Bh[128 * QBK];
    __shared__ __align__(16) half_t Bl[128 * QBK];

    const int tid  = threadIdx.x;
    const int lane = tid & 63, w = tid >> 6;
    const int wr = w >> 1, wc = w & 1;
    const int r16 = lane & 15, kq = lane >> 4;
    const int n0 = blockIdx.x * 128;
    const int m0 = blockIdx.y * 128;
    const bool three = (n0 < 1536);      // uniform per block

    // staging: thread tid covers row=tid>>2, col8=(tid&3)*8 of a 64-row round
    const half_t* ah = Fh  + (size_t)(m0 + (tid >> 2)) * D_ + (tid & 3) * 8;
    const half_t* al = Fl  + (size_t)(m0 + (tid >> 2)) * D_ + (tid & 3) * 8;
    const half_t* bh = Wth + (size_t)(n0 + (tid >> 2)) * D_ + (tid & 3) * 8;
    const half_t* bl = Wtl + (size_t)(n0 + (tid >> 2)) * D_ + (tid & 3) * 8;
    half_t* lAh = Ah + (w << 9);   // wave-uniform base; HW appends lane*16B
    half_t* lAl = Al + (w << 9);
    half_t* lBh = Bh + (w << 9);
    half_t* lBl = Bl + (w << 9);

    f32x4 acc[4][4];
#pragma unroll
    for (int mi = 0; mi < 4; ++mi)
#pragma unroll
        for (int ni = 0; ni < 4; ++ni) acc[mi][ni] = (f32x4)0.f;

    for (int kb = 0; kb < D_ / QBK; ++kb) {
#pragma unroll
        for (int i = 0; i < 2; ++i) {       // 2 rounds x 64 rows
            gload16(ah + (size_t)i * 64 * D_ + kb * QBK, lAh + i * 2048);
            gload16(bh + (size_t)i * 64 * D_ + kb * QBK, lBh + i * 2048);
        }
        if (three) {
#pragma unroll
            for (int i = 0; i < 2; ++i) {
                gload16(al + (size_t)i * 64 * D_ + kb * QBK, lAl + i * 2048);
                gload16(bl + (size_t)i * 64 * D_ + kb * QBK, lBl + i * 2048);
            }
        }
        __syncthreads();
        {
            half8 fa[4], fb[4];
#pragma unroll
            for (int mi = 0; mi < 4; ++mi)
                fa[mi] = *(const half8*)&Ah[(wr * 64 + mi * 16 + r16) * QBK + kq * 8];
#pragma unroll
            for (int ni = 0; ni < 4; ++ni)
                fb[ni] = *(const half8*)&Bh[(wc * 64 + ni * 16 + r16) * QBK + kq * 8];
#pragma unroll
            for (int mi = 0; mi < 4; ++mi)
#pragma unroll
                for (int ni = 0; ni < 4; ++ni)
                    acc[mi][ni] = __builtin_amdgcn_mfma_f32_16x16x32_f16(
                        fa[mi], fb[ni], acc[mi][ni], 0, 0, 0);
            if (three) {
                half8 gal[4], gbl[4];
#pragma unroll
                for (int mi = 0; mi < 4; ++mi)
                    gal[mi] = *(const half8*)&Al[(wr * 64 + mi * 16 + r16) * QBK + kq * 8];
#pragma unroll
                for (int ni = 0; ni < 4; ++ni)
                    gbl[ni] = *(const half8*)&Bl[(wc * 64 + ni * 16 + r16) * QBK + kq * 8];
#pragma unroll
                for (int mi = 0; mi < 4; ++mi)
#pragma unroll
                    for (int ni = 0; ni < 4; ++ni) {
                        acc[mi][ni] = __builtin_amdgcn_mfma_f32_16x16x32_f16(
                            fa[mi], gbl[ni], acc[mi][ni], 0, 0, 0);
                        acc[mi][ni] = __builtin_amdgcn_mfma_f32_16x16x32_f16(
                            gal[mi], fb[ni], acc[mi][ni], 0, 0, 0);
                    }
            }
        }
        __syncthreads();
    }

    const float unscale = 1.0f / 4096.0f;
#pragma unroll
    for (int ni = 0; ni < 4; ++ni) {
        const int n = n0 + wc * 64 + ni * 16 + r16;
        const float bias = (n0 < 768) ? bq[n] : bkv[n - 768];
        float* dst; int nn;
        if      (n0 < 768)  { dst = Q;  nn = n; }
        else if (n0 < 1536) { dst = Km; nn = n - 768; }
        else                { dst = Vm; nn = n - 1536; }
#pragma unroll
        for (int mi = 0; mi < 4; ++mi)
#pragma unroll
            for (int r = 0; r < 4; ++r) {
                const int m = m0 + wr * 64 + mi * 16 + kq * 4 + r;
                dst[(size_t)m * D_ + nn] = acc[mi][ni][r] * unscale + bias;
            }
    }
}

// ---------------------------------------------------------------------------
// Kernel 2: row L2 norms of Q,K + normalized bf16 copies + 1/norm.
// ---------------------------------------------------------------------------
__global__ __launch_bounds__(256) void norm_bf16(
    const float* __restrict__ Q, const float* __restrict__ Km,
    ushort* __restrict__ qn, ushort* __restrict__ kn,
    float* __restrict__ rqinv, float* __restrict__ rkinv)
{
    const int wid  = blockIdx.x * 4 + (threadIdx.x >> 6);
    const int lane = threadIdx.x & 63;
    const float* src; ushort* dst; float* rv; int r;
    if (wid < M_) { src = Q;  dst = qn; rv = rqinv; r = wid; }
    else          { src = Km; dst = kn; rv = rkinv; r = wid - M_; }
    const float* p = src + (size_t)r * D_ + lane * 12;
    float v[12];
#pragma unroll
    for (int i = 0; i < 3; ++i) *(float4*)&v[i * 4] = *(const float4*)&p[i * 4];
    float s = 0.f;
#pragma unroll
    for (int i = 0; i < 12; ++i) s += v[i] * v[i];
#pragma unroll
    for (int off = 32; off; off >>= 1) s += __shfl_xor(s, off);
    const float rinv = 1.0f / fmaxf(sqrtf(s), 1e-12f);
    ushort* op = dst + (size_t)r * D_ + lane * 12;
#pragma unroll
    for (int i = 0; i < 3; ++i) {
        ushort4 o;
        o.x = f2bf(v[i * 4 + 0] * rinv); o.y = f2bf(v[i * 4 + 1] * rinv);
        o.z = f2bf(v[i * 4 + 2] * rinv); o.w = f2bf(v[i * 4 + 3] * rinv);
        *(ushort4*)&op[i * 4] = o;
    }
    if (lane == 0) rv[r] = rinv;
}

// ---------------------------------------------------------------------------
// Kernel 3: bf16 MFMA sim GEMM (one batch), diagonal forced to bf16 lowest.
// ---------------------------------------------------------------------------
__global__ __launch_bounds__(256) void sim_gemm(
    const ushort* __restrict__ qn, const ushort* __restrict__ kn,
    ushort* __restrict__ S)
{
    __shared__ __align__(16) ushort As[128 * 64];
    __shared__ __align__(16) ushort Bs[128 * 64];

    const int tid  = threadIdx.x;
    const int lane = tid & 63, w = tid >> 6;
    const int wr = w >> 1, wc = w & 1;
    const int r16 = lane & 15, kq = lane >> 4;
    const int k0 = blockIdx.x * 128;
    const int q0 = blockIdx.y * 128;

    const ushort* qsrc = qn + (size_t)(q0 + (tid >> 3)) * D_ + (tid & 7) * 8;
    const ushort* ksrc = kn + (size_t)(k0 + (tid >> 3)) * D_ + (tid & 7) * 8;
    ushort* lA = As + ((tid >> 6) << 9);
    ushort* lB = Bs + ((tid >> 6) << 9);

    f32x4 acc[4][4];
#pragma unroll
    for (int mi = 0; mi < 4; ++mi)
#pragma unroll
        for (int ni = 0; ni < 4; ++ni) acc[mi][ni] = (f32x4)0.f;

    for (int kb = 0; kb < D_ / 64; ++kb) {
#pragma unroll
        for (int i = 0; i < 4; ++i) {
            gload16(qsrc + (size_t)i * 32 * D_ + kb * 64, lA + i * 2048);
            gload16(ksrc + (size_t)i * 32 * D_ + kb * 64, lB + i * 2048);
        }
        __syncthreads();
#pragma unroll
        for (int kk = 0; kk < 2; ++kk) {
            short8 a[4], bfr[4];
#pragma unroll
            for (int mi = 0; mi < 4; ++mi)
                a[mi] = *(const short8*)&As[(wr * 64 + mi * 16 + r16) * 64 + kk * 32 + kq * 8];
#pragma unroll
            for (int ni = 0; ni < 4; ++ni)
                bfr[ni] = *(const short8*)&Bs[(wc * 64 + ni * 16 + r16) * 64 + kk * 32 + kq * 8];
#pragma unroll
            for (int mi = 0; mi < 4; ++mi)
#pragma unroll
                for (int ni = 0; ni < 4; ++ni)
                    acc[mi][ni] = __builtin_amdgcn_mfma_f32_16x16x32_bf16(
                        a[mi], bfr[ni], acc[mi][ni], 0, 0, 0);
        }
        __syncthreads();
    }

#pragma unroll
    for (int mi = 0; mi < 4; ++mi)
#pragma unroll
        for (int ni = 0; ni < 4; ++ni)
#pragma unroll
            for (int r = 0; r < 4; ++r) {
                const int qq = q0 + wr * 64 + mi * 16 + kq * 4 + r;
                const int kk = k0 + wc * 64 + ni * 16 + r16;
                const float val = acc[mi][ni][r];
                const ushort bv = (qq == kk) ? (ushort)0xFF7Fu : f2bf(val);
                S[(size_t)qq * N_ + kk] = bv;
            }
}

// ---------------------------------------------------------------------------
// Kernel 4: branchless packed top-12 per (row, 256-wide k split).
// ---------------------------------------------------------------------------
__global__ __launch_bounds__(256) void sel_topk(
    const ushort* __restrict__ S, unsigned int* __restrict__ Part)
{
    const int tid = threadIdx.x;
    const int row = blockIdx.x * 256 + tid;
    const int ks  = blockIdx.y;
    const int kbase = ks * 256;
    const int KREV  = (N_ - 1) - kbase;

    const ushort* sp = S + (size_t)row * N_ + kbase;
    unsigned int t[TCAND];
#pragma unroll
    for (int i = 0; i < TCAND; ++i) t[i] = 0u;

    for (int j = 0; j < 256; j += 8) {
        const uint4 dv = *(const uint4*)(sp + j);
        unsigned int dw[4];
        dw[0] = dv.x; dw[1] = dv.y; dw[2] = dv.z; dw[3] = dv.w;
#pragma unroll
        for (int q = 0; q < 4; ++q) {
            const unsigned int vlo = dw[q] & 0xFFFFu;
            const unsigned int vhi = dw[q] >> 16;
            const unsigned int plo =
                ((vlo ^ (0x8000u + ((vlo >> 15) * 0x7FFFu))) << 16) |
                (unsigned int)(KREV - (j + 2 * q));
            const unsigned int phi =
                ((vhi ^ (0x8000u + ((vhi >> 15) * 0x7FFFu))) << 16) |
                (unsigned int)(KREV - (j + 2 * q + 1));
            unsigned int p = plo;
#pragma unroll
            for (int i = 0; i < TCAND; ++i) {
                const unsigned int mx = max(t[i], p);
                const unsigned int mn = min(t[i], p);
                t[i] = mx; p = mn;
            }
            p = phi;
#pragma unroll
            for (int i = 0; i < TCAND; ++i) {
                const unsigned int mx = max(t[i], p);
                const unsigned int mn = min(t[i], p);
                t[i] = mx; p = mn;
            }
        }
    }

    unsigned int* op = Part + (size_t)row * (KSPLIT * TCAND) + ks * TCAND;
#pragma unroll
    for (int i = 0; i < TCAND; ++i) op[i] = t[i];
}

// ---------------------------------------------------------------------------
// Kernel 5: zero output
// ---------------------------------------------------------------------------
__global__ void zero_out(float* __restrict__ out)
{
    const int i = blockIdx.x * 256 + threadIdx.x;
    if (i < B_ * D_) out[i] = 0.f;
}

// ---------------------------------------------------------------------------
// Kernel 6: merge 192 partials -> bf16 top-12 -> fp32 rescore -> exact top-8
// -> softmax -> V gather -> batch mean. One wave per row.
// ILP restructure: 36 gather loads issued in one dependence-free loop into
// 12 per-lane partial dots, then ONE 6-round butterfly on all 12 (12-way ILP)
// instead of 12 serial load+reduce chains.
// ---------------------------------------------------------------------------
__global__ __launch_bounds__(256) void merge_rescore_attn(
    const float* __restrict__ Q, const float* __restrict__ Kmat,
    const float* __restrict__ Vmat, const float* __restrict__ rqinv,
    const float* __restrict__ rkinv, const unsigned int* __restrict__ Part,
    float* __restrict__ out)
{
    __shared__ float laccum[4][D_];
    const int tid  = threadIdx.x;
    const int w    = tid >> 6, lane = tid & 63;
    const int row  = blockIdx.x * 4 + w;
    const int b    = row >> 12;

    // ---- load 192 packed candidates, extract top-12 by 12x wave-argmax ----
    const unsigned int* pp = Part + (size_t)row * (KSPLIT * TCAND);
    unsigned int c0 = pp[lane], c1 = pp[64 + lane], c2 = pp[128 + lane];
    unsigned int mysel = 0u;
#pragma unroll
    for (int it = 0; it < TCAND; ++it) {
        unsigned int m = max(c0, max(c1, c2));
#pragma unroll
        for (int off = 32; off; off >>= 1) m = max(m, __shfl_xor(m, off));
        c0 = (c0 == m) ? 0u : c0;
        c1 = (c1 == m) ? 0u : c1;
        c2 = (c2 == m) ? 0u : c2;
        mysel = (lane == it) ? m : mysel;
    }
    const int kj_lane = (N_ - 1) - (int)(mysel & 0xFFFFu);

    // ---- broadcast candidate indices, then ILP gather + partial dots ----
    int ka[TCAND];
#pragma unroll
    for (int j = 0; j < TCAND; ++j) ka[j] = __shfl(kj_lane, j);

    float qv[12];
    {
        const float* qp = Q + (size_t)row * D_ + lane * 12;
#pragma unroll
        for (int i = 0; i < 3; ++i) *(float4*)&qv[i * 4] = *(const float4*)&qp[i * 4];
    }
    const float rq = rqinv[row];
    const float scale = 0.03608439182435161f;   // 1/sqrt(768)

    float rkl[TCAND];
#pragma unroll
    for (int j = 0; j < TCAND; ++j) rkl[j] = rkinv[(b << 12) + ka[j]];

    float d[TCAND];
#pragma unroll
    for (int j = 0; j < TCAND; ++j) d[j] = 0.f;
#pragma unroll
    for (int j = 0; j < TCAND; ++j) {
        const float* kp = Kmat + ((size_t)(b << 12) + ka[j]) * D_ + lane * 12;
#pragma unroll
        for (int i = 0; i < 3; ++i) {
            const float4 kv = *(const float4*)&kp[i * 4];
            d[j] += qv[i * 4 + 0] * kv.x + qv[i * 4 + 1] * kv.y +
                    qv[i * 4 + 2] * kv.z + qv[i * 4 + 3] * kv.w;
        }
    }
    // one butterfly, all 12 values in flight
#pragma unroll
    for (int off = 32; off; off >>= 1)
#pragma unroll
        for (int j = 0; j < TCAND; ++j) d[j] += __shfl_xor(d[j], off);

    float simv[TCAND], lgv[TCAND];
#pragma unroll
    for (int j = 0; j < TCAND; ++j) {
        simv[j] = d[j] * rq * rkl[j];
        lgv[j]  = d[j] * scale;
    }

    // ---- exact top-8 of 12 by (sim desc, idx asc) ----
    int rk8[TCAND];
#pragma unroll
    for (int j = 0; j < TCAND; ++j) {
        int r = 0;
#pragma unroll
        for (int o = 0; o < TCAND; ++o) {
            if (o != j)
                r += (simv[o] > simv[j] ||
                      (simv[o] == simv[j] && ka[o] < ka[j])) ? 1 : 0;
        }
        rk8[j] = r;
    }

    // ---- softmax over the 8 winners ----
    float mx = -1e30f;
#pragma unroll
    for (int j = 0; j < TCAND; ++j) if (rk8[j] < KTOP) mx = fmaxf(mx, lgv[j]);
    float e[TCAND]; float ps = 0.f;
#pragma unroll
    for (int j = 0; j < TCAND; ++j) {
        const float ee = (rk8[j] < KTOP) ? expf(lgv[j] - mx) : 0.f;
        e[j] = ee; ps += ee;
    }
    const float inv = 1.0f / ps;

    // ---- weighted V sum (rk8 is lane-uniform -> wave-uniform branches) ----
    float oacc[12];
#pragma unroll
    for (int i = 0; i < 12; ++i) oacc[i] = 0.f;
#pragma unroll
    for (int j = 0; j < TCAND; ++j) {
        if (rk8[j] < KTOP) {
            const float p = e[j] * inv;
            const float* vp = Vmat + ((size_t)(b << 12) + ka[j]) * D_ + lane * 12;
#pragma unroll
            for (int i = 0; i < 3; ++i) {
                const float4 vv = *(const float4*)&vp[i * 4];
                oacc[i * 4 + 0] += p * vv.x; oacc[i * 4 + 1] += p * vv.y;
                oacc[i * 4 + 2] += p * vv.z; oacc[i * 4 + 3] += p * vv.w;
            }
        }
    }

#pragma unroll
    for (int i = 0; i < 3; ++i)
        *(float4*)&laccum[w][lane * 12 + i * 4] = *(float4*)&oacc[i * 4];
    __syncthreads();
    for (int dd = tid; dd < D_; dd += 256) {
        const float s = laccum[0][dd] + laccum[1][dd] + laccum[2][dd] + laccum[3][dd];
        atomicAdd(&out[(size_t)b * D_ + dd], s * (1.0f / N_));
    }
}

// ---------------------------------------------------------------------------
extern "C" void kernel_launch(void* const* d_in, const int* in_sizes, int n_in,
                              void* d_out, int out_size, void* d_ws, size_t ws_size,
                              hipStream_t stream)
{
    const float* feats = (const float*)d_in[0];
    const float* Wq    = (const float*)d_in[1];
    const float* bq    = (const float*)d_in[2];
    const float* Wkv   = (const float*)d_in[3];
    const float* bkv   = (const float*)d_in[4];
    float* out = (float*)d_out;

    // workspace layout (~254 MB); Fh/Fl alias qn/kn (disjoint liveness).
    char* ws = (char*)d_ws;
    size_t off = 0;
    float*  Q    = (float*)(ws + off);  off += (size_t)M_ * D_ * sizeof(float);
    float*  Km   = (float*)(ws + off);  off += (size_t)M_ * D_ * sizeof(float);
    float*  Vm   = (float*)(ws + off);  off += (size_t)M_ * D_ * sizeof(float);
    char*   unio = ws + off;            off += 2 * (size_t)M_ * D_ * sizeof(ushort);
    half_t* Fh   = (half_t*)unio;
    half_t* Fl   = (half_t*)(unio + (size_t)M_ * D_ * sizeof(half_t));
    ushort* qn   = (ushort*)unio;
    ushort* kn   = (ushort*)(unio + (size_t)M_ * D_ * sizeof(ushort));
    float*  rqv  = (float*)(ws + off);  off += (size_t)M_ * sizeof(float);
    float*  rkv  = (float*)(ws + off);  off += (size_t)M_ * sizeof(float);
    half_t* Wth  = (half_t*)(ws + off); off += (size_t)2304 * D_ * sizeof(half_t);
    half_t* Wtl  = (half_t*)(ws + off); off += (size_t)2304 * D_ * sizeof(half_t);
    ushort* S    = (ushort*)(ws + off); off += (size_t)N_ * N_ * sizeof(ushort);
    unsigned int* Part = (unsigned int*)(ws + off);
    off += (size_t)M_ * KSPLIT * TCAND * sizeof(unsigned int);
    (void)ws_size; (void)in_sizes; (void)n_in; (void)out_size;

    split_feats<<<(M_ * D_) / 1024, 256, 0, stream>>>(feats, Fh, Fl);
    split_w<<<dim3(2304 / 64, D_ / 64), 256, 0, stream>>>(Wq, Wkv, Wth, Wtl);
    qkv_mfma<<<dim3(2304 / 128, M_ / 128), 256, 0, stream>>>(
        Fh, Fl, Wth, Wtl, bq, bkv, Q, Km, Vm);
    norm_bf16<<<(2 * M_) / 4, 256, 0, stream>>>(Q, Km, qn, kn, rqv, rkv);

    for (int b = 0; b < B_; ++b) {
        sim_gemm<<<dim3(N_ / 128, N_ / 128), 256, 0, stream>>>(
            qn + (size_t)b * N_ * D_, kn + (size_t)b * N_ * D_, S);
        sel_topk<<<dim3(N_ / 256, KSPLIT), 256, 0, stream>>>(
            S, Part + (size_t)b * N_ * (KSPLIT * TCAND));
    }

    zero_out<<<(B_ * D_ + 255) / 256, 256, 0, stream>>>(out);
    merge_rescore_attn<<<M_ / 4, 256, 0, stream>>>(
        Q, Km, Vm, rqv, rkv, Part, out);
}

// Round 8
// 646.197 us; speedup vs baseline: 1.1284x; 1.1284x over previous
//
#include <hip/hip_runtime.h>
#include <hip/hip_bf16.h>
#include <math.h>

#define B_ 4
#define N_ 4096
#define D_ 768
#define KTOP 8
#define M_ (B_*N_)          // 16384
#define TCAND 12            // bf16 candidates kept per row chunk
#define SELK 32             // 32 chunks of 128 k per row

typedef __attribute__((ext_vector_type(8))) short short8;
typedef __attribute__((ext_vector_type(4))) float f32x4;
typedef _Float16 half_t;
typedef __attribute__((ext_vector_type(8))) _Float16 half8;
typedef __attribute__((ext_vector_type(4))) _Float16 half4;

__device__ __forceinline__ ushort f2bf(float f) {
    unsigned int u = __float_as_uint(f);
    unsigned int r = (u + 0x7FFFu + ((u >> 16) & 1u)) >> 16;
    return (ushort)r;
}

__device__ __forceinline__ void gload16(const void* g, void* l) {
    __builtin_amdgcn_global_load_lds(
        (const __attribute__((address_space(1))) unsigned int*)g,
        (__attribute__((address_space(3))) unsigned int*)l, 16, 0, 0);
}

// ---------------------------------------------------------------------------
// Kernel 1a: split feats into fp16 hi/lo (Dekker 2-way split).
// ---------------------------------------------------------------------------
__global__ __launch_bounds__(256) void split_feats(
    const float* __restrict__ f, half_t* __restrict__ Fh, half_t* __restrict__ Fl)
{
    const int i = (blockIdx.x * 256 + threadIdx.x) * 4;   // exact coverage
    const float4 v = *(const float4*)&f[i];
    float x[4] = {v.x, v.y, v.z, v.w};
    half4 h, l;
#pragma unroll
    for (int c = 0; c < 4; ++c) {
        const half_t hh = (half_t)x[c];
        h[c] = hh;
        l[c] = (half_t)(x[c] - (float)hh);
    }
    *(half4*)&Fh[i] = h;
    *(half4*)&Fl[i] = l;
}

// ---------------------------------------------------------------------------
// Kernel 1b: build W^T fp16 hi/lo splits, scaled by 2^12 (exact).
// ---------------------------------------------------------------------------
__global__ __launch_bounds__(256) void split_w(
    const float* __restrict__ Wq, const float* __restrict__ Wkv,
    half_t* __restrict__ Wth, half_t* __restrict__ Wtl)
{
    __shared__ float T[64][65];
    const int tid = threadIdx.x;
    const int n0 = blockIdx.x * 64;     // dest row block (output col)
    const int k0 = blockIdx.y * 64;     // dest col block (contraction)

    const int nl = tid & 63;
#pragma unroll
    for (int r = 0; r < 16; ++r) {
        const int kl = (tid >> 6) * 16 + r;
        const int n  = n0 + nl;
        const float w = (n < 768)
            ? Wq[(size_t)(k0 + kl) * 768 + n]
            : Wkv[(size_t)(k0 + kl) * 1536 + (n - 768)];
        T[kl][nl] = w;
    }
    __syncthreads();

    const int kl2 = tid & 63;
#pragma unroll
    for (int r = 0; r < 16; ++r) {
        const int nl2 = (tid >> 6) * 16 + r;
        const float ws = T[kl2][nl2] * 4096.0f;
        const half_t h = (half_t)ws;
        const half_t l = (half_t)(ws - (float)h);
        Wth[(size_t)(n0 + nl2) * D_ + k0 + kl2] = h;
        Wtl[(size_t)(n0 + nl2) * D_ + k0 + kl2] = l;
    }
}

// ---------------------------------------------------------------------------
// Kernel 1c: QKV projection via fp16-split MFMA. BK=64 (round-5 config:
// measured 193.6us vs BK=32's 200us / +47% FETCH from 64B-of-128B lines).
// QK region: 3 MFMA terms (hh, hl, lh); V region: hh only.
// ---------------------------------------------------------------------------
__global__ __launch_bounds__(256) void qkv_mfma(
    const half_t* __restrict__ Fh, const half_t* __restrict__ Fl,
    const half_t* __restrict__ Wth, const half_t* __restrict__ Wtl,
    const float* __restrict__ bq, const float* __restrict__ bkv,
    float* __restrict__ Q, float* __restrict__ Km, float* __restrict__ Vm)
{
    __shared__ __align__(16) half_t Ah[128 * 64];
    __shared__ __align__(16) half_t Al[128 * 64];
    __shared__ __align__(16) half_t Bh[128 * 64];
    __shared__ __align__(16) half_t Bl[128 * 64];

    const int tid  = threadIdx.x;
    const int lane = tid & 63, w = tid >> 6;
    const int wr = w >> 1, wc = w & 1;
    const int r16 = lane & 15, kq = lane >> 4;
    const int n0 = blockIdx.x * 128;
    const int m0 = blockIdx.y * 128;
    const bool three = (n0 < 1536);      // uniform per block

    const half_t* ah = Fh  + (size_t)(m0 + (tid >> 3)) * D_ + (tid & 7) * 8;
    const half_t* al = Fl  + (size_t)(m0 + (tid >> 3)) * D_ + (tid & 7) * 8;
    const half_t* bh = Wth + (size_t)(n0 + (tid >> 3)) * D_ + (tid & 7) * 8;
    const half_t* bl = Wtl + (size_t)(n0 + (tid >> 3)) * D_ + (tid & 7) * 8;
    half_t* lAh = Ah + (w << 9);   // wave-uniform base; HW appends lane*16B
    half_t* lAl = Al + (w << 9);
    half_t* lBh = Bh + (w << 9);
    half_t* lBl = Bl + (w << 9);

    f32x4 acc[4][4];
#pragma unroll
    for (int mi = 0; mi < 4; ++mi)
#pragma unroll
        for (int ni = 0; ni < 4; ++ni) acc[mi][ni] = (f32x4)0.f;

    for (int kb = 0; kb < D_ / 64; ++kb) {
#pragma unroll
        for (int i = 0; i < 4; ++i) {
            gload16(ah + (size_t)i * 32 * D_ + kb * 64, lAh + i * 2048);
            gload16(bh + (size_t)i * 32 * D_ + kb * 64, lBh + i * 2048);
        }
        if (three) {
#pragma unroll
            for (int i = 0; i < 4; ++i) {
                gload16(al + (size_t)i * 32 * D_ + kb * 64, lAl + i * 2048);
                gload16(bl + (size_t)i * 32 * D_ + kb * 64, lBl + i * 2048);
            }
        }
        __syncthreads();
#pragma unroll
        for (int kk = 0; kk < 2; ++kk) {
            half8 fa[4], fb[4];
#pragma unroll
            for (int mi = 0; mi < 4; ++mi)
                fa[mi] = *(const half8*)&Ah[(wr * 64 + mi * 16 + r16) * 64 + kk * 32 + kq * 8];
#pragma unroll
            for (int ni = 0; ni < 4; ++ni)
                fb[ni] = *(const half8*)&Bh[(wc * 64 + ni * 16 + r16) * 64 + kk * 32 + kq * 8];
#pragma unroll
            for (int mi = 0; mi < 4; ++mi)
#pragma unroll
                for (int ni = 0; ni < 4; ++ni)
                    acc[mi][ni] = __builtin_amdgcn_mfma_f32_16x16x32_f16(
                        fa[mi], fb[ni], acc[mi][ni], 0, 0, 0);
            if (three) {
                half8 gal[4], gbl[4];
#pragma unroll
                for (int mi = 0; mi < 4; ++mi)
                    gal[mi] = *(const half8*)&Al[(wr * 64 + mi * 16 + r16) * 64 + kk * 32 + kq * 8];
#pragma unroll
                for (int ni = 0; ni < 4; ++ni)
                    gbl[ni] = *(const half8*)&Bl[(wc * 64 + ni * 16 + r16) * 64 + kk * 32 + kq * 8];
#pragma unroll
                for (int mi = 0; mi < 4; ++mi)
#pragma unroll
                    for (int ni = 0; ni < 4; ++ni) {
                        acc[mi][ni] = __builtin_amdgcn_mfma_f32_16x16x32_f16(
                            fa[mi], gbl[ni], acc[mi][ni], 0, 0, 0);
                        acc[mi][ni] = __builtin_amdgcn_mfma_f32_16x16x32_f16(
                            gal[mi], fb[ni], acc[mi][ni], 0, 0, 0);
                    }
            }
        }
        __syncthreads();
    }

    const float unscale = 1.0f / 4096.0f;
#pragma unroll
    for (int ni = 0; ni < 4; ++ni) {
        const int n = n0 + wc * 64 + ni * 16 + r16;
        const float bias = (n0 < 768) ? bq[n] : bkv[n - 768];
        float* dst; int nn;
        if      (n0 < 768)  { dst = Q;  nn = n; }
        else if (n0 < 1536) { dst = Km; nn = n - 768; }
        else                { dst = Vm; nn = n - 1536; }
#pragma unroll
        for (int mi = 0; mi < 4; ++mi)
#pragma unroll
            for (int r = 0; r < 4; ++r) {
                const int m = m0 + wr * 64 + mi * 16 + kq * 4 + r;
                dst[(size_t)m * D_ + nn] = acc[mi][ni][r] * unscale + bias;
            }
    }
}

// ---------------------------------------------------------------------------
// Kernel 2: row L2 norms of Q,K + normalized bf16 copies + 1/norm.
// ---------------------------------------------------------------------------
__global__ __launch_bounds__(256) void norm_bf16(
    const float* __restrict__ Q, const float* __restrict__ Km,
    ushort* __restrict__ qn, ushort* __restrict__ kn,
    float* __restrict__ rqinv, float* __restrict__ rkinv)
{
    const int wid  = blockIdx.x * 4 + (threadIdx.x >> 6);
    const int lane = threadIdx.x & 63;
    const float* src; ushort* dst; float* rv; int r;
    if (wid < M_) { src = Q;  dst = qn; rv = rqinv; r = wid; }
    else          { src = Km; dst = kn; rv = rkinv; r = wid - M_; }
    const float* p = src + (size_t)r * D_ + lane * 12;
    float v[12];
#pragma unroll
    for (int i = 0; i < 3; ++i) *(float4*)&v[i * 4] = *(const float4*)&p[i * 4];
    float s = 0.f;
#pragma unroll
    for (int i = 0; i < 12; ++i) s += v[i] * v[i];
#pragma unroll
    for (int off = 32; off; off >>= 1) s += __shfl_xor(s, off);
    const float rinv = 1.0f / fmaxf(sqrtf(s), 1e-12f);
    ushort* op = dst + (size_t)r * D_ + lane * 12;
#pragma unroll
    for (int i = 0; i < 3; ++i) {
        ushort4 o;
        o.x = f2bf(v[i * 4 + 0] * rinv); o.y = f2bf(v[i * 4 + 1] * rinv);
        o.z = f2bf(v[i * 4 + 2] * rinv); o.w = f2bf(v[i * 4 + 3] * rinv);
        *(ushort4*)&op[i * 4] = o;
    }
    if (lane == 0) rv[r] = rinv;
}

// ---------------------------------------------------------------------------
// Kernel 3: FUSED bf16 MFMA sim GEMM + in-block top-12 select.
// Grid (32 kblk, 32 qblk, 4 batch). No S matrix: the 128x128 bf16 tile goes
// to LDS (aliasing the dead staging buffers), each thread runs the packed
// 12-ladder over a contiguous 64-value half-row, halves pair-merge via LDS,
// 12 candidates per (row, 128-k chunk) written to Part. Diagonal forced to
// bf16 lowest. Packing: sortable(bf16)<<16 | (4095-k)  (value desc, k asc).
// ---------------------------------------------------------------------------
__global__ __launch_bounds__(256) void sim_topk_fused(
    const ushort* __restrict__ qn_all, const ushort* __restrict__ kn_all,
    unsigned int* __restrict__ Part)
{
    __shared__ __align__(16) ushort smem[128 * 136];   // 34.8 KB
    ushort* As = smem;                 // [128*64] staging, dead after K-loop
    ushort* Bs = smem + 128 * 64;

    const int tid  = threadIdx.x;
    const int lane = tid & 63, w = tid >> 6;
    const int wr = w >> 1, wc = w & 1;
    const int r16 = lane & 15, kq = lane >> 4;
    const int k0 = blockIdx.x * 128;
    const int q0 = blockIdx.y * 128;
    const int b  = blockIdx.z;

    const ushort* qsrc = qn_all + ((size_t)b * N_ + q0 + (tid >> 3)) * D_ + (tid & 7) * 8;
    const ushort* ksrc = kn_all + ((size_t)b * N_ + k0 + (tid >> 3)) * D_ + (tid & 7) * 8;
    ushort* lA = As + (w << 9);
    ushort* lB = Bs + (w << 9);

    f32x4 acc[4][4];
#pragma unroll
    for (int mi = 0; mi < 4; ++mi)
#pragma unroll
        for (int ni = 0; ni < 4; ++ni) acc[mi][ni] = (f32x4)0.f;

    for (int kb = 0; kb < D_ / 64; ++kb) {
#pragma unroll
        for (int i = 0; i < 4; ++i) {
            gload16(qsrc + (size_t)i * 32 * D_ + kb * 64, lA + i * 2048);
            gload16(ksrc + (size_t)i * 32 * D_ + kb * 64, lB + i * 2048);
        }
        __syncthreads();
#pragma unroll
        for (int kk = 0; kk < 2; ++kk) {
            short8 a[4], bfr[4];
#pragma unroll
            for (int mi = 0; mi < 4; ++mi)
                a[mi] = *(const short8*)&As[(wr * 64 + mi * 16 + r16) * 64 + kk * 32 + kq * 8];
#pragma unroll
            for (int ni = 0; ni < 4; ++ni)
                bfr[ni] = *(const short8*)&Bs[(wc * 64 + ni * 16 + r16) * 64 + kk * 32 + kq * 8];
#pragma unroll
            for (int mi = 0; mi < 4; ++mi)
#pragma unroll
                for (int ni = 0; ni < 4; ++ni)
                    acc[mi][ni] = __builtin_amdgcn_mfma_f32_16x16x32_bf16(
                        a[mi], bfr[ni], acc[mi][ni], 0, 0, 0);
        }
        __syncthreads();
    }

    // ---- epilogue: bf16 tile -> LDS (row stride 136 ushorts) ----
    ushort* St = smem;
#pragma unroll
    for (int mi = 0; mi < 4; ++mi)
#pragma unroll
        for (int ni = 0; ni < 4; ++ni)
#pragma unroll
            for (int r = 0; r < 4; ++r) {
                const int row = wr * 64 + mi * 16 + kq * 4 + r;
                const int col = wc * 64 + ni * 16 + r16;
                const bool diag = (q0 + row) == (k0 + col);
                St[row * 136 + col] = diag ? (ushort)0xFF7Fu : f2bf(acc[mi][ni][r]);
            }
    __syncthreads();

    // ---- per-thread packed 12-ladder over a contiguous 64-value half-row ----
    const int rrow = tid >> 1, half = tid & 1;
    const int KREV = (N_ - 1) - (k0 + half * 64);
    const ushort* sp = St + rrow * 136 + half * 64;
    unsigned int t[TCAND];
#pragma unroll
    for (int i = 0; i < TCAND; ++i) t[i] = 0u;

#pragma unroll
    for (int j = 0; j < 64; j += 8) {
        const uint4 dv = *(const uint4*)(sp + j);
        unsigned int dw[4];
        dw[0] = dv.x; dw[1] = dv.y; dw[2] = dv.z; dw[3] = dv.w;
#pragma unroll
        for (int q = 0; q < 4; ++q) {
            const unsigned int vlo = dw[q] & 0xFFFFu;
            const unsigned int vhi = dw[q] >> 16;
            const unsigned int plo =
                ((vlo ^ (0x8000u + ((vlo >> 15) * 0x7FFFu))) << 16) |
                (unsigned int)(KREV - (j + 2 * q));
            const unsigned int phi =
                ((vhi ^ (0x8000u + ((vhi >> 15) * 0x7FFFu))) << 16) |
                (unsigned int)(KREV - (j + 2 * q + 1));
            unsigned int p = plo;
#pragma unroll
            for (int i = 0; i < TCAND; ++i) {
                const unsigned int mx = max(t[i], p);
                const unsigned int mn = min(t[i], p);
                t[i] = mx; p = mn;
            }
            p = phi;
#pragma unroll
            for (int i = 0; i < TCAND; ++i) {
                const unsigned int mx = max(t[i], p);
                const unsigned int mn = min(t[i], p);
                t[i] = mx; p = mn;
            }
        }
    }
    __syncthreads();              // Stile dead; reuse smem as uint scratch

    unsigned int* scratch = (unsigned int*)smem;
    if (half) {
#pragma unroll
        for (int i = 0; i < TCAND; ++i) scratch[rrow * TCAND + i] = t[i];
    }
    __syncthreads();
    if (!half) {
#pragma unroll
        for (int i = 0; i < TCAND; ++i) {
            unsigned int p = scratch[rrow * TCAND + i];
#pragma unroll
            for (int s = 0; s < TCAND; ++s) {
                const unsigned int mx = max(t[s], p);
                const unsigned int mn = min(t[s], p);
                t[s] = mx; p = mn;
            }
        }
        unsigned int* op = Part +
            ((size_t)(b * N_ + q0 + rrow) * SELK + (k0 >> 7)) * TCAND;
#pragma unroll
        for (int i = 0; i < TCAND; ++i) op[i] = t[i];
    }
}

// ---------------------------------------------------------------------------
// Kernel 4: zero output
// ---------------------------------------------------------------------------
__global__ void zero_out(float* __restrict__ out)
{
    const int i = blockIdx.x * 256 + threadIdx.x;
    if (i < B_ * D_) out[i] = 0.f;
}

// ---------------------------------------------------------------------------
// Kernel 5: merge 384 partials -> bf16 top-12 -> fp32 rescore -> exact top-8
// -> softmax -> V gather -> batch mean. One wave per row.
// ---------------------------------------------------------------------------
__global__ __launch_bounds__(256) void merge_rescore_attn(
    const float* __restrict__ Q, const float* __restrict__ Kmat,
    const float* __restrict__ Vmat, const float* __restrict__ rqinv,
    const float* __restrict__ rkinv, const unsigned int* __restrict__ Part,
    float* __restrict__ out)
{
    __shared__ float laccum[4][D_];
    const int tid  = threadIdx.x;
    const int w    = tid >> 6, lane = tid & 63;
    const int row  = blockIdx.x * 4 + w;
    const int b    = row >> 12;

    // ---- 384 packed candidates (6 regs/lane), top-12 by 12x wave-argmax ----
    const unsigned int* pp = Part + (size_t)row * (SELK * TCAND);
    unsigned int c[6];
#pragma unroll
    for (int i = 0; i < 6; ++i) c[i] = pp[i * 64 + lane];
    unsigned int mysel = 0u;
#pragma unroll
    for (int it = 0; it < TCAND; ++it) {
        unsigned int m = c[0];
#pragma unroll
        for (int i = 1; i < 6; ++i) m = max(m, c[i]);
#pragma unroll
        for (int off = 32; off; off >>= 1) m = max(m, __shfl_xor(m, off));
#pragma unroll
        for (int i = 0; i < 6; ++i) c[i] = (c[i] == m) ? 0u : c[i];
        mysel = (lane == it) ? m : mysel;
    }
    const int kj_lane = (N_ - 1) - (int)(mysel & 0xFFFFu);

    // ---- broadcast candidate indices, then ILP gather + partial dots ----
    int ka[TCAND];
#pragma unroll
    for (int j = 0; j < TCAND; ++j) ka[j] = __shfl(kj_lane, j);

    float qv[12];
    {
        const float* qp = Q + (size_t)row * D_ + lane * 12;
#pragma unroll
        for (int i = 0; i < 3; ++i) *(float4*)&qv[i * 4] = *(const float4*)&qp[i * 4];
    }
    const float rq = rqinv[row];
    const float scale = 0.03608439182435161f;   // 1/sqrt(768)

    float rkl[TCAND];
#pragma unroll
    for (int j = 0; j < TCAND; ++j) rkl[j] = rkinv[(b << 12) + ka[j]];

    float d[TCAND];
#pragma unroll
    for (int j = 0; j < TCAND; ++j) d[j] = 0.f;
#pragma unroll
    for (int j = 0; j < TCAND; ++j) {
        const float* kp = Kmat + ((size_t)(b << 12) + ka[j]) * D_ + lane * 12;
#pragma unroll
        for (int i = 0; i < 3; ++i) {
            const float4 kv = *(const float4*)&kp[i * 4];
            d[j] += qv[i * 4 + 0] * kv.x + qv[i * 4 + 1] * kv.y +
                    qv[i * 4 + 2] * kv.z + qv[i * 4 + 3] * kv.w;
        }
    }
#pragma unroll
    for (int off = 32; off; off >>= 1)
#pragma unroll
        for (int j = 0; j < TCAND; ++j) d[j] += __shfl_xor(d[j], off);

    float simv[TCAND], lgv[TCAND];
#pragma unroll
    for (int j = 0; j < TCAND; ++j) {
        simv[j] = d[j] * rq * rkl[j];
        lgv[j]  = d[j] * scale;
    }

    // ---- exact top-8 of 12 by (sim desc, idx asc) ----
    int rk8[TCAND];
#pragma unroll
    for (int j = 0; j < TCAND; ++j) {
        int r = 0;
#pragma unroll
        for (int o = 0; o < TCAND; ++o) {
            if (o != j)
                r += (simv[o] > simv[j] ||
                      (simv[o] == simv[j] && ka[o] < ka[j])) ? 1 : 0;
        }
        rk8[j] = r;
    }

    // ---- softmax over the 8 winners ----
    float mx = -1e30f;
#pragma unroll
    for (int j = 0; j < TCAND; ++j) if (rk8[j] < KTOP) mx = fmaxf(mx, lgv[j]);
    float e[TCAND]; float ps = 0.f;
#pragma unroll
    for (int j = 0; j < TCAND; ++j) {
        const float ee = (rk8[j] < KTOP) ? expf(lgv[j] - mx) : 0.f;
        e[j] = ee; ps += ee;
    }
    const float inv = 1.0f / ps;

    // ---- weighted V sum (rk8 lane-uniform -> wave-uniform branches) ----
    float oacc[12];
#pragma unroll
    for (int i = 0; i < 12; ++i) oacc[i] = 0.f;
#pragma unroll
    for (int j = 0; j < TCAND; ++j) {
        if (rk8[j] < KTOP) {
            const float p = e[j] * inv;
            const float* vp = Vmat + ((size_t)(b << 12) + ka[j]) * D_ + lane * 12;
#pragma unroll
            for (int i = 0; i < 3; ++i) {
                const float4 vv = *(const float4*)&vp[i * 4];
                oacc[i * 4 + 0] += p * vv.x; oacc[i * 4 + 1] += p * vv.y;
                oacc[i * 4 + 2] += p * vv.z; oacc[i * 4 + 3] += p * vv.w;
            }
        }
    }

#pragma unroll
    for (int i = 0; i < 3; ++i)
        *(float4*)&laccum[w][lane * 12 + i * 4] = *(float4*)&oacc[i * 4];
    __syncthreads();
    for (int dd = tid; dd < D_; dd += 256) {
        const float s = laccum[0][dd] + laccum[1][dd] + laccum[2][dd] + laccum[3][dd];
        atomicAdd(&out[(size_t)b * D_ + dd], s * (1.0f / N_));
    }
}

// ---------------------------------------------------------------------------
extern "C" void kernel_launch(void* const* d_in, const int* in_sizes, int n_in,
                              void* d_out, int out_size, void* d_ws, size_t ws_size,
                              hipStream_t stream)
{
    const float* feats = (const float*)d_in[0];
    const float* Wq    = (const float*)d_in[1];
    const float* bq    = (const float*)d_in[2];
    const float* Wkv   = (const float*)d_in[3];
    const float* bkv   = (const float*)d_in[4];
    float* out = (float*)d_out;

    // workspace layout (~233 MB); Fh/Fl alias qn/kn (disjoint liveness).
    char* ws = (char*)d_ws;
    size_t off = 0;
    float*  Q    = (float*)(ws + off);  off += (size_t)M_ * D_ * sizeof(float);
    float*  Km   = (float*)(ws + off);  off += (size_t)M_ * D_ * sizeof(float);
    float*  Vm   = (float*)(ws + off);  off += (size_t)M_ * D_ * sizeof(float);
    char*   unio = ws + off;            off += 2 * (size_t)M_ * D_ * sizeof(ushort);
    half_t* Fh   = (half_t*)unio;
    half_t* Fl   = (half_t*)(unio + (size_t)M_ * D_ * sizeof(half_t));
    ushort* qn   = (ushort*)unio;
    ushort* kn   = (ushort*)(unio + (size_t)M_ * D_ * sizeof(ushort));
    float*  rqv  = (float*)(ws + off);  off += (size_t)M_ * sizeof(float);
    float*  rkv  = (float*)(ws + off);  off += (size_t)M_ * sizeof(float);
    half_t* Wth  = (half_t*)(ws + off); off += (size_t)2304 * D_ * sizeof(half_t);
    half_t* Wtl  = (half_t*)(ws + off); off += (size_t)2304 * D_ * sizeof(half_t);
    unsigned int* Part = (unsigned int*)(ws + off);
    off += (size_t)M_ * SELK * TCAND * sizeof(unsigned int);   // 25.2 MB
    (void)ws_size; (void)in_sizes; (void)n_in; (void)out_size;

    split_feats<<<(M_ * D_) / 1024, 256, 0, stream>>>(feats, Fh, Fl);
    split_w<<<dim3(2304 / 64, D_ / 64), 256, 0, stream>>>(Wq, Wkv, Wth, Wtl);
    qkv_mfma<<<dim3(2304 / 128, M_ / 128), 256, 0, stream>>>(
        Fh, Fl, Wth, Wtl, bq, bkv, Q, Km, Vm);
    norm_bf16<<<(2 * M_) / 4, 256, 0, stream>>>(Q, Km, qn, kn, rqv, rkv);

    sim_topk_fused<<<dim3(N_ / 128, N_ / 128, B_), 256, 0, stream>>>(qn, kn, Part);

    zero_out<<<(B_ * D_ + 255) / 256, 256, 0, stream>>>(out);
    merge_rescore_attn<<<M_ / 4, 256, 0, stream>>>(
        Q, Km, Vm, rqv, rkv, Part, out);
}